// Round 5
// baseline (334.707 us; speedup 1.0000x reference)
//
#include <hip/hip_runtime.h>
#include <cstdint>
#include <cstddef>

// Problem constants
#define BB   2
#define SS   2048
#define DD   512
#define HH   8
#define HDIM 64

typedef __attribute__((ext_vector_type(8)))  short          s16x8;
typedef __attribute__((ext_vector_type(8)))  unsigned short u16x8;
typedef __attribute__((ext_vector_type(16))) float          f32x16;

static __device__ __forceinline__ unsigned short f2bf(float f) {
  union { float f; unsigned u; } x; x.f = f;
  unsigned r = x.u + 0x7fffu + ((x.u >> 16) & 1u);  // RNE
  return (unsigned short)(r >> 16);
}
// truncating bf16 pack: result = bf(hi)<<16 | bf(lo), ONE v_perm_b32
static __device__ __forceinline__ unsigned packtrunc(float lo, float hi) {
  return __builtin_amdgcn_perm(__float_as_uint(hi), __float_as_uint(lo), 0x07060302u);
}

// sigmoid scale folded into Q: -1/sqrt(64) * log2(e)
#define QSCALE (-0.18033688011111543f)

// ---------------- fused cvt + QKV projection ---------------------------------------
// grid (M/64=64, N/64=8, 3) = 1536 blocks = 6/CU. 256 threads = 4 waves in 2x2,
// each wave 32x32 out via one 32x32x16 MFMA chain. Reg-prefetch + LDS dbuf.
// Outputs (all bf16):
//   z=0 Q: head-split [B][H][S][HD], pre-scaled by QSCALE
//   z=1 K: MFMA A-frag order:  [bh][kt=s/32][c=d/16][ lane=(d8&1)*32+(s&31) ][ j=d&7 ]
//   z=2 V: MFMA B-frag order:  [bh][kt=s/32][dh=d/32][cc=(s/16)&1][ lane=((s/8)&1)*32+(d&31) ][ j=s&7 ]
// so attn loads every fragment as ONE contiguous 1KB dwordx4 stream.
__global__ __launch_bounds__(256) void proj_kernel(
    const float* __restrict__ x,
    const float* __restrict__ wq, const float* __restrict__ wk, const float* __restrict__ wv,
    const float* __restrict__ bq, const float* __restrict__ bk, const float* __restrict__ bv,
    unsigned short* __restrict__ qo, unsigned short* __restrict__ ko,
    unsigned short* __restrict__ vt) {
  __shared__ unsigned short As[2][64 * 40];  // 64 x 32 bf16, pad->40
  __shared__ unsigned short Bs[2][64 * 40];

  const int z = blockIdx.z;
  const float* w; const float* bias;
  if (z == 0)      { w = wq; bias = bq; }
  else if (z == 1) { w = wk; bias = bk; }
  else             { w = wv; bias = bv; }

  const int t = threadIdx.x;
  const int lane = t & 63, wave = t >> 6;
  const int ln = lane & 31, hi = lane >> 5;
  const int wr = wave >> 1, wc = wave & 1;
  const int m0 = blockIdx.x * 64, n0 = blockIdx.y * 64;

  // staging: 512 float4 chunks per matrix, 2 per thread
  float4 ar[2], br[2];
#pragma unroll
  for (int i = 0; i < 2; i++) {
    int c = t + i * 256;
    ar[i] = *(const float4*)&x[(size_t)(m0 + (c >> 3)) * DD + (c & 7) * 4];
    br[i] = *(const float4*)&w[(size_t)(n0 + (c >> 3)) * DD + (c & 7) * 4];
  }
#pragma unroll
  for (int i = 0; i < 2; i++) {
    int c = t + i * 256;
    uint2 ua, ub;
    ua.x = packtrunc(ar[i].x, ar[i].y); ua.y = packtrunc(ar[i].z, ar[i].w);
    ub.x = packtrunc(br[i].x, br[i].y); ub.y = packtrunc(br[i].z, br[i].w);
    *(uint2*)&As[0][(c >> 3) * 40 + (c & 7) * 4] = ua;
    *(uint2*)&Bs[0][(c >> 3) * 40 + (c & 7) * 4] = ub;
  }
  __syncthreads();

  f32x16 acc = {};

#pragma unroll 2
  for (int kt = 0; kt < 16; kt++) {
    const int cur = kt & 1, nxt = cur ^ 1;
    if (kt < 15) {
      int k0 = (kt + 1) * 32;
#pragma unroll
      for (int i = 0; i < 2; i++) {
        int c = t + i * 256;
        ar[i] = *(const float4*)&x[(size_t)(m0 + (c >> 3)) * DD + k0 + (c & 7) * 4];
        br[i] = *(const float4*)&w[(size_t)(n0 + (c >> 3)) * DD + k0 + (c & 7) * 4];
      }
    }
#pragma unroll
    for (int c = 0; c < 2; c++) {
      s16x8 af = *(const s16x8*)&As[cur][(wr * 32 + ln) * 40 + c * 16 + hi * 8];
      s16x8 bf = *(const s16x8*)&Bs[cur][(wc * 32 + ln) * 40 + c * 16 + hi * 8];
      acc = __builtin_amdgcn_mfma_f32_32x32x16_bf16(af, bf, acc, 0, 0, 0);
    }
    if (kt < 15) {
#pragma unroll
      for (int i = 0; i < 2; i++) {
        int c = t + i * 256;
        uint2 ua, ub;
        ua.x = packtrunc(ar[i].x, ar[i].y); ua.y = packtrunc(ar[i].z, ar[i].w);
        ub.x = packtrunc(br[i].x, br[i].y); ub.y = packtrunc(br[i].z, br[i].w);
        *(uint2*)&As[nxt][(c >> 3) * 40 + (c & 7) * 4] = ua;
        *(uint2*)&Bs[nxt][(c >> 3) * 40 + (c & 7) * 4] = ub;
      }
    }
    __syncthreads();
  }

  // Epilogue. C layout: col(n) = ln, row(m) local = (r&3) + 8*(r>>2) + 4*hi.
  const int h = blockIdx.y;
  const int bidx = m0 >> 11;
  const int sbase = (m0 & 2047) + wr * 32;   // multiple of 32
  const int hd = wc * 32 + ln;
  const float bval = bias[n0 + hd];
  const size_t bhb = (size_t)(bidx * HH + h) * SS * HDIM;

  if (z == 0) {  // Q: [bh][s][hd], scaled
#pragma unroll
    for (int r = 0; r < 16; r++) {
      int s = sbase + (r & 3) + 8 * (r >> 2) + 4 * hi;
      qo[bhb + (size_t)s * HDIM + hd] = f2bf((acc[r] + bval) * QSCALE);
    }
  } else if (z == 1) {  // K fragment order
    const int c = hd >> 4, hk = (hd >> 3) & 1, j = hd & 7;
    const int kts = sbase >> 5;
    unsigned short* kd = ko + bhb + ((size_t)kts * 4 + c) * 512 + j;
#pragma unroll
    for (int r = 0; r < 16; r++) {
      int off = (r & 3) + 8 * (r >> 2) + 4 * hi;  // s & 31
      kd[(hk * 32 + off) * 8] = f2bf(acc[r] + bval);
    }
  } else {  // V fragment order; s,s+1 adjacent in j -> dword stores
    const int kts = sbase >> 5;
    unsigned short* vd = vt + bhb + ((size_t)kts * 4 + wc * 2) * 512 + ln * 8 + 4 * hi;
#pragma unroll
    for (int g = 0; g < 4; g++) {
      unsigned short* vg = vd + ((g >> 1) * 512) + (g & 1) * 256;
#pragma unroll
      for (int j = 0; j < 4; j += 2) {
        unsigned pk = (unsigned)f2bf(acc[g * 4 + j] + bval) |
                      ((unsigned)f2bf(acc[g * 4 + j + 1] + bval) << 16);
        *(unsigned*)&vg[j] = pk;
      }
    }
  }
}

// ---------------- fused sigmoid attention: frag-direct loads, no K-loop LDS ---------
// grid (32, 16); 256 threads = 4 waves; block = 64 queries; wave owns key quarter
// (16 tiles of 32, strided 4). K/V fragments are CONTIGUOUS 1KB dwordx4 loads
// (frag-ordered by proj), register double-buffered. Zero barriers in the loop.
// 32 KB staged O-reduction -> 4 blocks/CU.
__global__ __launch_bounds__(256, 4) void attn_kernel(
    const unsigned short* __restrict__ qb,
    const unsigned short* __restrict__ kfb,
    const unsigned short* __restrict__ vfb,
    float* __restrict__ out) {
  __shared__ __align__(16) float red[2 * 4096];  // 32 KB

  const int t = threadIdx.x;
  const int lane = t & 63, wave = t >> 6;
  const int ln = lane & 31, hi = lane >> 5;
  // XCD swizzle: blocks of one bh all land on XCD bh%8 (16 ≡ 0 mod 8)
  const int fid = blockIdx.y * 32 + blockIdx.x;
  const int bh = fid & 15, qx = fid >> 4;
  const int b = bh >> 3, h = bh & 7;
  const unsigned short* qp = qb + (size_t)bh * SS * HDIM;
  const unsigned short* kfp = kfb + (size_t)bh * SS * HDIM;
  const unsigned short* vfp = vfb + (size_t)bh * SS * HDIM;
  const int q0 = qx * 64;

  // Q fragments (B-operand: n=q on lane, k=d), whole kernel in regs
  s16x8 qf[2][4];
#pragma unroll
  for (int qs = 0; qs < 2; qs++)
#pragma unroll
    for (int c = 0; c < 4; c++)
      qf[qs][c] = *(const s16x8*)&qp[(size_t)(q0 + qs * 32 + ln) * HDIM + c * 16 + hi * 8];

  f32x16 o00 = {}, o01 = {}, o10 = {}, o11 = {};

  // frag-ordered: chunk(kt_glob, sub) at (kt_glob*4+sub)*512 + lane*8; this wave's
  // tile i has kt_glob = i*4 + wave -> base advances 8192 per i.
  s16x8 kf[2][4], vf[2][4];
  int koff = wave * 4 * 512 + lane * 8;
  int voff = koff;
#pragma unroll
  for (int c = 0; c < 4; c++) {
    kf[0][c] = *(const s16x8*)&kfp[koff + c * 512];
    vf[0][c] = *(const s16x8*)&vfp[voff + c * 512];
  }
  koff += 8192; voff += 8192;

#pragma unroll 2
  for (int i = 0; i < 16; i++) {
    const int cur = i & 1, nxt = cur ^ 1;
    if (i < 15) {  // prefetch next tile's fragments (contiguous streams)
#pragma unroll
      for (int c = 0; c < 4; c++) {
        kf[nxt][c] = *(const s16x8*)&kfp[koff + c * 512];
        vf[nxt][c] = *(const s16x8*)&vfp[voff + c * 512];
      }
      koff += 8192; voff += 8192;
    }

    // QK^T: S^T[key_local on (r,hi)][q on ln], two q-subtiles
    f32x16 st0 = {}, st1 = {};
#pragma unroll
    for (int c = 0; c < 4; c++) {
      st0 = __builtin_amdgcn_mfma_f32_32x32x16_bf16(kf[cur][c], qf[0][c], st0, 0, 0, 0);
      st1 = __builtin_amdgcn_mfma_f32_32x32x16_bf16(kf[cur][c], qf[1][c], st1, 0, 0, 0);
    }

    // sigmoid = rcp(1 + exp2(st)) (scale folded into Q), truncating bf16 pack
    unsigned pgx[2][4], pgy[2][4];
#pragma unroll
    for (int qs = 0; qs < 2; qs++) {
      f32x16 stq = qs ? st1 : st0;
#pragma unroll
      for (int g = 0; g < 4; g++) {
        float p0 = __builtin_amdgcn_rcpf(1.0f + __builtin_amdgcn_exp2f(stq[4 * g + 0]));
        float p1 = __builtin_amdgcn_rcpf(1.0f + __builtin_amdgcn_exp2f(stq[4 * g + 1]));
        float p2 = __builtin_amdgcn_rcpf(1.0f + __builtin_amdgcn_exp2f(stq[4 * g + 2]));
        float p3 = __builtin_amdgcn_rcpf(1.0f + __builtin_amdgcn_exp2f(stq[4 * g + 3]));
        pgx[qs][g] = packtrunc(p0, p1);
        pgy[qs][g] = packtrunc(p2, p3);
      }
    }

    // PV: A-operand P built via lane^32 exchange (validated pattern)
#pragma unroll
    for (int c = 0; c < 2; c++) {
      const int gk = 2 * c + hi, gs = 2 * c + (hi ^ 1);
#pragma unroll
      for (int qs = 0; qs < 2; qs++) {
        unsigned rx = __shfl_xor((int)pgx[qs][gs], 32, 64);
        unsigned ry = __shfl_xor((int)pgy[qs][gs], 32, 64);
        union { unsigned u[4]; s16x8 v; } pu;
        pu.u[0] = hi ? rx : pgx[qs][gk];
        pu.u[1] = hi ? ry : pgy[qs][gk];
        pu.u[2] = hi ? pgx[qs][gk] : rx;
        pu.u[3] = hi ? pgy[qs][gk] : ry;
        if (qs == 0) {
          o00 = __builtin_amdgcn_mfma_f32_32x32x16_bf16(pu.v, vf[cur][c], o00, 0, 0, 0);
          o01 = __builtin_amdgcn_mfma_f32_32x32x16_bf16(pu.v, vf[cur][2 + c], o01, 0, 0, 0);
        } else {
          o10 = __builtin_amdgcn_mfma_f32_32x32x16_bf16(pu.v, vf[cur][c], o10, 0, 0, 0);
          o11 = __builtin_amdgcn_mfma_f32_32x32x16_bf16(pu.v, vf[cur][2 + c], o11, 0, 0, 0);
        }
      }
    }
  }

  // staged 4->2->1 cross-wave O reduction in 32 KB
  if (wave >= 2) {
#pragma unroll
    for (int qs = 0; qs < 2; qs++)
#pragma unroll
      for (int dh = 0; dh < 2; dh++) {
        f32x16 ov = qs ? (dh ? o11 : o10) : (dh ? o01 : o00);
#pragma unroll
        for (int r = 0; r < 16; r++) {
          int ql = qs * 32 + (r & 3) + 8 * (r >> 2) + 4 * hi;
          red[(wave - 2) * 4096 + ql * 64 + dh * 32 + ln] = ov[r];
        }
      }
  }
  __syncthreads();
  if (wave < 2) {
#pragma unroll
    for (int qs = 0; qs < 2; qs++)
#pragma unroll
      for (int dh = 0; dh < 2; dh++) {
        f32x16 ov = qs ? (dh ? o11 : o10) : (dh ? o01 : o00);
#pragma unroll
        for (int r = 0; r < 16; r++) {
          int ql = qs * 32 + (r & 3) + 8 * (r >> 2) + 4 * hi;
          int idx = wave * 4096 + ql * 64 + dh * 32 + ln;
          red[idx] += ov[r];
        }
      }
  }
  __syncthreads();
  const float4* r0 = (const float4*)red;
  const float4* r1 = (const float4*)(red + 4096);
#pragma unroll
  for (int j = 0; j < 4; j++) {
    int g = t + j * 256;
    float4 s0 = r0[g], s1 = r1[g];
    float4 s;
    s.x = s0.x + s1.x; s.y = s0.y + s1.y; s.z = s0.z + s1.z; s.w = s0.w + s1.w;
    int q = g >> 4, dbase = (g & 15) * 4;
    *(float4*)&out[((size_t)(b * SS + q0 + q)) * DD + h * HDIM + dbase] = s;
  }
}

extern "C" void kernel_launch(void* const* d_in, const int* in_sizes, int n_in,
                              void* d_out, int out_size, void* d_ws, size_t ws_size,
                              hipStream_t stream) {
  const float* x  = (const float*)d_in[0];
  const float* wq = (const float*)d_in[1];
  const float* bq = (const float*)d_in[2];
  const float* wk = (const float*)d_in[3];
  const float* bk = (const float*)d_in[4];
  const float* wv = (const float*)d_in[5];
  const float* bv = (const float*)d_in[6];
  float* out = (float*)d_out;

  constexpr size_t XN = (size_t)BB * SS * DD;

  unsigned short* qo = (unsigned short*)d_ws;
  unsigned short* ko = qo + XN;
  unsigned short* vt = ko + XN;  // 12 MB total ws use

  proj_kernel<<<dim3(64, 8, 3), 256, 0, stream>>>(x, wq, wk, wv, bq, bk, bv, qo, ko, vt);
  attn_kernel<<<dim3(SS / 64, BB * HH), 256, 0, stream>>>(qo, ko, vt, out);
}

// Round 6
// 133.227 us; speedup vs baseline: 2.5123x; 2.5123x over previous
//
#include <hip/hip_runtime.h>
#include <cstdint>
#include <cstddef>

// Problem constants
#define BB   2
#define SS   2048
#define DD   512
#define HH   8
#define HDIM 64

typedef __attribute__((ext_vector_type(8)))  short          s16x8;
typedef __attribute__((ext_vector_type(8)))  unsigned short u16x8;
typedef __attribute__((ext_vector_type(16))) float          f32x16;

static __device__ __forceinline__ unsigned short f2bf(float f) {
  union { float f; unsigned u; } x; x.f = f;
  unsigned r = x.u + 0x7fffu + ((x.u >> 16) & 1u);  // RNE
  return (unsigned short)(r >> 16);
}
// truncating bf16 pack: result = bf(hi)<<16 | bf(lo), ONE v_perm_b32
static __device__ __forceinline__ unsigned packtrunc(float lo, float hi) {
  return __builtin_amdgcn_perm(__float_as_uint(hi), __float_as_uint(lo), 0x07060302u);
}

// sigmoid scale folded into Q: -1/sqrt(64) * log2(e)
#define QSCALE (-0.18033688011111543f)

// ---------------- fused cvt + QKV projection ---------------------------------------
// grid (M/64=64, N/64=8, 3) = 1536 blocks = 6/CU. 256 threads = 4 waves in 2x2,
// each wave 32x32 out via one 32x32x16 MFMA chain. Reg-prefetch + LDS dbuf.
// Outputs (all bf16):
//   z=0 Q: head-split [B][H][S][HD], pre-scaled by QSCALE
//   z=1 K: MFMA A-frag order:  [bh][kt=s/32][c=d/16][ lane=(d8&1)*32+(s&31) ][ j=d&7 ]
//   z=2 V: MFMA B-frag order:  [bh][kt=s/32][dh=d/32][cc=(s/16)&1][ lane=((s/8)&1)*32+(d&31) ][ j=s&7 ]
// so attn loads every fragment as ONE contiguous 1KB dwordx4 stream.
__global__ __launch_bounds__(256) void proj_kernel(
    const float* __restrict__ x,
    const float* __restrict__ wq, const float* __restrict__ wk, const float* __restrict__ wv,
    const float* __restrict__ bq, const float* __restrict__ bk, const float* __restrict__ bv,
    unsigned short* __restrict__ qo, unsigned short* __restrict__ ko,
    unsigned short* __restrict__ vt) {
  __shared__ unsigned short As[2][64 * 40];  // 64 x 32 bf16, pad->40
  __shared__ unsigned short Bs[2][64 * 40];

  const int z = blockIdx.z;
  const float* w; const float* bias;
  if (z == 0)      { w = wq; bias = bq; }
  else if (z == 1) { w = wk; bias = bk; }
  else             { w = wv; bias = bv; }

  const int t = threadIdx.x;
  const int lane = t & 63, wave = t >> 6;
  const int ln = lane & 31, hi = lane >> 5;
  const int wr = wave >> 1, wc = wave & 1;
  const int m0 = blockIdx.x * 64, n0 = blockIdx.y * 64;

  // staging: 512 float4 chunks per matrix, 2 per thread
  float4 ar[2], br[2];
#pragma unroll
  for (int i = 0; i < 2; i++) {
    int c = t + i * 256;
    ar[i] = *(const float4*)&x[(size_t)(m0 + (c >> 3)) * DD + (c & 7) * 4];
    br[i] = *(const float4*)&w[(size_t)(n0 + (c >> 3)) * DD + (c & 7) * 4];
  }
#pragma unroll
  for (int i = 0; i < 2; i++) {
    int c = t + i * 256;
    uint2 ua, ub;
    ua.x = packtrunc(ar[i].x, ar[i].y); ua.y = packtrunc(ar[i].z, ar[i].w);
    ub.x = packtrunc(br[i].x, br[i].y); ub.y = packtrunc(br[i].z, br[i].w);
    *(uint2*)&As[0][(c >> 3) * 40 + (c & 7) * 4] = ua;
    *(uint2*)&Bs[0][(c >> 3) * 40 + (c & 7) * 4] = ub;
  }
  __syncthreads();

  f32x16 acc = {};

#pragma unroll 2
  for (int kt = 0; kt < 16; kt++) {
    const int cur = kt & 1, nxt = cur ^ 1;
    if (kt < 15) {
      int k0 = (kt + 1) * 32;
#pragma unroll
      for (int i = 0; i < 2; i++) {
        int c = t + i * 256;
        ar[i] = *(const float4*)&x[(size_t)(m0 + (c >> 3)) * DD + k0 + (c & 7) * 4];
        br[i] = *(const float4*)&w[(size_t)(n0 + (c >> 3)) * DD + k0 + (c & 7) * 4];
      }
    }
#pragma unroll
    for (int c = 0; c < 2; c++) {
      s16x8 af = *(const s16x8*)&As[cur][(wr * 32 + ln) * 40 + c * 16 + hi * 8];
      s16x8 bf = *(const s16x8*)&Bs[cur][(wc * 32 + ln) * 40 + c * 16 + hi * 8];
      acc = __builtin_amdgcn_mfma_f32_32x32x16_bf16(af, bf, acc, 0, 0, 0);
    }
    if (kt < 15) {
#pragma unroll
      for (int i = 0; i < 2; i++) {
        int c = t + i * 256;
        uint2 ua, ub;
        ua.x = packtrunc(ar[i].x, ar[i].y); ua.y = packtrunc(ar[i].z, ar[i].w);
        ub.x = packtrunc(br[i].x, br[i].y); ub.y = packtrunc(br[i].z, br[i].w);
        *(uint2*)&As[nxt][(c >> 3) * 40 + (c & 7) * 4] = ua;
        *(uint2*)&Bs[nxt][(c >> 3) * 40 + (c & 7) * 4] = ub;
      }
    }
    __syncthreads();
  }

  // Epilogue. C layout: col(n) = ln, row(m) local = (r&3) + 8*(r>>2) + 4*hi.
  const int h = blockIdx.y;
  const int bidx = m0 >> 11;
  const int sbase = (m0 & 2047) + wr * 32;   // multiple of 32
  const int hd = wc * 32 + ln;
  const float bval = bias[n0 + hd];
  const size_t bhb = (size_t)(bidx * HH + h) * SS * HDIM;

  if (z == 0) {  // Q: [bh][s][hd], scaled
#pragma unroll
    for (int r = 0; r < 16; r++) {
      int s = sbase + (r & 3) + 8 * (r >> 2) + 4 * hi;
      qo[bhb + (size_t)s * HDIM + hd] = f2bf((acc[r] + bval) * QSCALE);
    }
  } else if (z == 1) {  // K fragment order
    const int c = hd >> 4, hk = (hd >> 3) & 1, j = hd & 7;
    const int kts = sbase >> 5;
    unsigned short* kd = ko + bhb + ((size_t)kts * 4 + c) * 512 + j;
#pragma unroll
    for (int r = 0; r < 16; r++) {
      int off = (r & 3) + 8 * (r >> 2) + 4 * hi;  // s & 31
      kd[(hk * 32 + off) * 8] = f2bf(acc[r] + bval);
    }
  } else {  // V fragment order; s,s+1 adjacent in j -> dword stores
    const int kts = sbase >> 5;
    unsigned short* vd = vt + bhb + ((size_t)kts * 4 + wc * 2) * 512 + ln * 8 + 4 * hi;
#pragma unroll
    for (int g = 0; g < 4; g++) {
      unsigned short* vg = vd + ((g >> 1) * 512) + (g & 1) * 256;
#pragma unroll
      for (int j = 0; j < 4; j += 2) {
        unsigned pk = (unsigned)f2bf(acc[g * 4 + j] + bval) |
                      ((unsigned)f2bf(acc[g * 4 + j + 1] + bval) << 16);
        *(unsigned*)&vg[j] = pk;
      }
    }
  }
}

// ---------------- fused sigmoid attention: frag-direct loads, no K-loop LDS ---------
// grid (32, 16); 256 threads = 4 waves; block = 64 queries; wave owns key quarter
// (16 tiles of 32, strided 4). K/V fragments are CONTIGUOUS 1KB dwordx4 loads
// (frag-ordered by proj), register double-buffered. Zero barriers in the loop.
// launch_bounds (256,2): cap 256 unified regs/wave — (256,4) spilled (R5: 573 MB
// scratch writes). 2 blocks/CU * 512 blocks fills the chip exactly.
__global__ __launch_bounds__(256, 2) void attn_kernel(
    const unsigned short* __restrict__ qb,
    const unsigned short* __restrict__ kfb,
    const unsigned short* __restrict__ vfb,
    float* __restrict__ out) {
  __shared__ __align__(16) float red[2 * 4096];  // 32 KB

  const int t = threadIdx.x;
  const int lane = t & 63, wave = t >> 6;
  const int ln = lane & 31, hi = lane >> 5;
  // XCD swizzle: blocks of one bh all land on XCD bh%8 (16 ≡ 0 mod 8)
  const int fid = blockIdx.y * 32 + blockIdx.x;
  const int bh = fid & 15, qx = fid >> 4;
  const int b = bh >> 3, h = bh & 7;
  const unsigned short* qp = qb + (size_t)bh * SS * HDIM;
  const unsigned short* kfp = kfb + (size_t)bh * SS * HDIM;
  const unsigned short* vfp = vfb + (size_t)bh * SS * HDIM;
  const int q0 = qx * 64;

  // Q fragments (B-operand: n=q on lane, k=d), whole kernel in regs
  s16x8 qf[2][4];
#pragma unroll
  for (int qs = 0; qs < 2; qs++)
#pragma unroll
    for (int c = 0; c < 4; c++)
      qf[qs][c] = *(const s16x8*)&qp[(size_t)(q0 + qs * 32 + ln) * HDIM + c * 16 + hi * 8];

  f32x16 o00 = {}, o01 = {}, o10 = {}, o11 = {};

  // frag-ordered: chunk(kt_glob, sub) at (kt_glob*4+sub)*512 + lane*8; this wave's
  // tile i has kt_glob = i*4 + wave -> base advances 8192 per i.
  s16x8 kf[2][4], vf[2][4];
  int foff = wave * 4 * 512 + lane * 8;
#pragma unroll
  for (int c = 0; c < 4; c++) {
    kf[0][c] = *(const s16x8*)&kfp[foff + c * 512];
    vf[0][c] = *(const s16x8*)&vfp[foff + c * 512];
  }
  foff += 8192;

#pragma unroll 2
  for (int i = 0; i < 16; i++) {
    const int cur = i & 1, nxt = cur ^ 1;
    if (i < 15) {  // prefetch next tile's fragments (contiguous streams)
#pragma unroll
      for (int c = 0; c < 4; c++) {
        kf[nxt][c] = *(const s16x8*)&kfp[foff + c * 512];
        vf[nxt][c] = *(const s16x8*)&vfp[foff + c * 512];
      }
      foff += 8192;
    }

    // QK^T: S^T[key_local on (r,hi)][q on ln], two q-subtiles
    f32x16 st0 = {}, st1 = {};
#pragma unroll
    for (int c = 0; c < 4; c++) {
      st0 = __builtin_amdgcn_mfma_f32_32x32x16_bf16(kf[cur][c], qf[0][c], st0, 0, 0, 0);
      st1 = __builtin_amdgcn_mfma_f32_32x32x16_bf16(kf[cur][c], qf[1][c], st1, 0, 0, 0);
    }

    // sigmoid = rcp(1 + exp2(st)) (scale folded into Q), truncating bf16 pack
    unsigned pgx[2][4], pgy[2][4];
#pragma unroll
    for (int qs = 0; qs < 2; qs++) {
      f32x16 stq = qs ? st1 : st0;
#pragma unroll
      for (int g = 0; g < 4; g++) {
        float p0 = __builtin_amdgcn_rcpf(1.0f + __builtin_amdgcn_exp2f(stq[4 * g + 0]));
        float p1 = __builtin_amdgcn_rcpf(1.0f + __builtin_amdgcn_exp2f(stq[4 * g + 1]));
        float p2 = __builtin_amdgcn_rcpf(1.0f + __builtin_amdgcn_exp2f(stq[4 * g + 2]));
        float p3 = __builtin_amdgcn_rcpf(1.0f + __builtin_amdgcn_exp2f(stq[4 * g + 3]));
        pgx[qs][g] = packtrunc(p0, p1);
        pgy[qs][g] = packtrunc(p2, p3);
      }
    }

    // PV: A-operand P built via lane^32 exchange (validated pattern)
#pragma unroll
    for (int c = 0; c < 2; c++) {
      const int gk = 2 * c + hi, gs = 2 * c + (hi ^ 1);
#pragma unroll
      for (int qs = 0; qs < 2; qs++) {
        unsigned rx = __shfl_xor((int)pgx[qs][gs], 32, 64);
        unsigned ry = __shfl_xor((int)pgy[qs][gs], 32, 64);
        union { unsigned u[4]; s16x8 v; } pu;
        pu.u[0] = hi ? rx : pgx[qs][gk];
        pu.u[1] = hi ? ry : pgy[qs][gk];
        pu.u[2] = hi ? pgx[qs][gk] : rx;
        pu.u[3] = hi ? pgy[qs][gk] : ry;
        if (qs == 0) {
          o00 = __builtin_amdgcn_mfma_f32_32x32x16_bf16(pu.v, vf[cur][c], o00, 0, 0, 0);
          o01 = __builtin_amdgcn_mfma_f32_32x32x16_bf16(pu.v, vf[cur][2 + c], o01, 0, 0, 0);
        } else {
          o10 = __builtin_amdgcn_mfma_f32_32x32x16_bf16(pu.v, vf[cur][c], o10, 0, 0, 0);
          o11 = __builtin_amdgcn_mfma_f32_32x32x16_bf16(pu.v, vf[cur][2 + c], o11, 0, 0, 0);
        }
      }
    }
  }

  // staged 4->2->1 cross-wave O reduction in 32 KB
  if (wave >= 2) {
#pragma unroll
    for (int qs = 0; qs < 2; qs++)
#pragma unroll
      for (int dh = 0; dh < 2; dh++) {
        f32x16 ov = qs ? (dh ? o11 : o10) : (dh ? o01 : o00);
#pragma unroll
        for (int r = 0; r < 16; r++) {
          int ql = qs * 32 + (r & 3) + 8 * (r >> 2) + 4 * hi;
          red[(wave - 2) * 4096 + ql * 64 + dh * 32 + ln] = ov[r];
        }
      }
  }
  __syncthreads();
  if (wave < 2) {
#pragma unroll
    for (int qs = 0; qs < 2; qs++)
#pragma unroll
      for (int dh = 0; dh < 2; dh++) {
        f32x16 ov = qs ? (dh ? o11 : o10) : (dh ? o01 : o00);
#pragma unroll
        for (int r = 0; r < 16; r++) {
          int ql = qs * 32 + (r & 3) + 8 * (r >> 2) + 4 * hi;
          int idx = wave * 4096 + ql * 64 + dh * 32 + ln;
          red[idx] += ov[r];
        }
      }
  }
  __syncthreads();
  const float4* r0 = (const float4*)red;
  const float4* r1 = (const float4*)(red + 4096);
#pragma unroll
  for (int j = 0; j < 4; j++) {
    int g = t + j * 256;
    float4 s0 = r0[g], s1 = r1[g];
    float4 s;
    s.x = s0.x + s1.x; s.y = s0.y + s1.y; s.z = s0.z + s1.z; s.w = s0.w + s1.w;
    int q = g >> 4, dbase = (g & 15) * 4;
    *(float4*)&out[((size_t)(b * SS + q0 + q)) * DD + h * HDIM + dbase] = s;
  }
}

extern "C" void kernel_launch(void* const* d_in, const int* in_sizes, int n_in,
                              void* d_out, int out_size, void* d_ws, size_t ws_size,
                              hipStream_t stream) {
  const float* x  = (const float*)d_in[0];
  const float* wq = (const float*)d_in[1];
  const float* bq = (const float*)d_in[2];
  const float* wk = (const float*)d_in[3];
  const float* bk = (const float*)d_in[4];
  const float* wv = (const float*)d_in[5];
  const float* bv = (const float*)d_in[6];
  float* out = (float*)d_out;

  constexpr size_t XN = (size_t)BB * SS * DD;

  unsigned short* qo = (unsigned short*)d_ws;
  unsigned short* ko = qo + XN;
  unsigned short* vt = ko + XN;  // 12 MB total ws use

  proj_kernel<<<dim3(64, 8, 3), 256, 0, stream>>>(x, wq, wk, wv, bq, bk, bv, qo, ko, vt);
  attn_kernel<<<dim3(SS / 64, BB * HH), 256, 0, stream>>>(qo, ko, vt, out);
}